// Round 2
// baseline (545.744 us; speedup 1.0000x reference)
//
#include <hip/hip_runtime.h>
#include <cstddef>

#define LN_EPS 1e-5f

__device__ inline float4 ld4(const float* p) { return *reinterpret_cast<const float4*>(p); }
__device__ inline void st4(float* p, float4 v) { *reinterpret_cast<float4*>(p) = v; }

// ---------------- full-K GEMM + bias (x_in). grid 64, block 256. scalar-A (SGPR) path.
__global__ __launch_bounds__(256) void gemm_bias(const float* __restrict__ A,
                                                 const float* __restrict__ W,
                                                 const float* __restrict__ bias,
                                                 float* __restrict__ out, int K) {
  const int row0 = blockIdx.x * 16, c = threadIdx.x;
  float acc[16];
#pragma unroll
  for (int r = 0; r < 16; ++r) acc[r] = 0.f;
  const float* wp = W + c;
#pragma unroll 2
  for (int k = 0; k < K; k += 4) {
    float w0 = wp[(size_t)k * 256];
    float w1 = wp[(size_t)(k + 1) * 256];
    float w2 = wp[(size_t)(k + 2) * 256];
    float w3 = wp[(size_t)(k + 3) * 256];
#pragma unroll
    for (int r = 0; r < 16; ++r) {
      float4 a = ld4(&A[(size_t)(row0 + r) * K + k]);  // uniform -> s_load_dwordx4
      acc[r] = fmaf(a.x, w0, acc[r]);
      acc[r] = fmaf(a.y, w1, acc[r]);
      acc[r] = fmaf(a.z, w2, acc[r]);
      acc[r] = fmaf(a.w, w3, acc[r]);
    }
  }
  float b = bias[c];
#pragma unroll
  for (int r = 0; r < 16; ++r) out[(size_t)(row0 + r) * 256 + c] = acc[r] + b;
}

// ---------------- K-split GEMM partials: part[kc][row][c]. grid (64,4), block 256. scalar-A.
__global__ __launch_bounds__(256) void gemm_part(const float* __restrict__ A,
                                                 const float* __restrict__ W,
                                                 float* __restrict__ part,
                                                 int K, int KC) {
  const int row0 = blockIdx.x * 16, c = threadIdx.x;
  const int kcs = blockIdx.y * KC;
  float acc[16];
#pragma unroll
  for (int r = 0; r < 16; ++r) acc[r] = 0.f;
  const float* wp = W + c;
#pragma unroll 2
  for (int k = kcs; k < kcs + KC; k += 4) {
    float w0 = wp[(size_t)k * 256];
    float w1 = wp[(size_t)(k + 1) * 256];
    float w2 = wp[(size_t)(k + 2) * 256];
    float w3 = wp[(size_t)(k + 3) * 256];
#pragma unroll
    for (int r = 0; r < 16; ++r) {
      float4 a = ld4(&A[(size_t)(row0 + r) * K + k]);  // uniform -> s_load_dwordx4
      acc[r] = fmaf(a.x, w0, acc[r]);
      acc[r] = fmaf(a.y, w1, acc[r]);
      acc[r] = fmaf(a.z, w2, acc[r]);
      acc[r] = fmaf(a.w, w3, acc[r]);
    }
  }
  float* pp = part + (((size_t)blockIdx.y * 1024 + row0) << 8) + c;
#pragma unroll
  for (int r = 0; r < 16; ++r) pp[(size_t)r * 256] = acc[r];
}

// ---------------- fused adjacency: xp partial-sum staging + relu-d-reduce + sigmoid -> pred
// grid (8 n-tiles, 8 e-tiles, 4 b), block 256. 32x32 tile, full d=256 in two 128-halves.
__global__ __launch_bounds__(256) void adjfull(const float* __restrict__ part,
                                               const float* __restrict__ incold,
                                               const float* __restrict__ wi,
                                               const float* __restrict__ bi,
                                               const float* __restrict__ bx,
                                               const float* __restrict__ ws,
                                               const float* __restrict__ bs,
                                               float* __restrict__ pred) {
  __shared__ float lds[2 * 32 * 132];
  float* tn = lds;
  float* te = lds + 32 * 132;
  const int n0 = blockIdx.x * 32, e0 = blockIdx.y * 32, b = blockIdx.z;
  const int tid = threadIdx.x;
  const size_t rb = (size_t)b * 256;
  const int tx = tid & 15, ty = tid >> 4;
  float incv[2][2], acc[2][2];
#pragma unroll
  for (int j = 0; j < 2; ++j)
#pragma unroll
    for (int i = 0; i < 2; ++i) {
      incv[j][i] = incold[((rb + e0 + ty + 16 * j) << 8) + n0 + tx + 16 * i];
      acc[j][i] = 0.f;
    }
  for (int dh = 0; dh < 256; dh += 128) {
    if (dh) __syncthreads();
#pragma unroll
    for (int s = 0; s < 4; ++s) {
      int idx = tid + s * 256;          // 0..1023
      int row = idx >> 5;               // 0..31
      int d = dh + (idx & 31) * 4;      // within [dh, dh+128)
      float4 bxv = ld4(&bx[d]);
      {
        size_t o = ((rb + n0 + row) << 8) + d;
        float4 p0 = ld4(&part[o]);
        float4 p1 = ld4(&part[o + 262144]);
        float4 p2 = ld4(&part[o + 524288]);
        float4 p3 = ld4(&part[o + 786432]);
        float4 v;
        v.x = p0.x + p1.x + p2.x + p3.x + bxv.x;
        v.y = p0.y + p1.y + p2.y + p3.y + bxv.y;
        v.z = p0.z + p1.z + p2.z + p3.z + bxv.z;
        v.w = p0.w + p1.w + p2.w + p3.w + bxv.w;
        st4(&tn[row * 132 + (d - dh)], v);
      }
      {
        size_t o = ((rb + e0 + row) << 8) + d;
        float4 p0 = ld4(&part[o]);
        float4 p1 = ld4(&part[o + 262144]);
        float4 p2 = ld4(&part[o + 524288]);
        float4 p3 = ld4(&part[o + 786432]);
        float4 bv = ld4(&bi[d]);
        float4 v;
        v.x = p0.x + p1.x + p2.x + p3.x + bxv.x + bv.x;
        v.y = p0.y + p1.y + p2.y + p3.y + bxv.y + bv.y;
        v.z = p0.z + p1.z + p2.z + p3.z + bxv.z + bv.z;
        v.w = p0.w + p1.w + p2.w + p3.w + bxv.w + bv.w;
        st4(&te[row * 132 + (d - dh)], v);
      }
    }
    __syncthreads();
#pragma unroll 4
    for (int dl = 0; dl < 128; dl += 4) {
      float4 wiq = ld4(&wi[dh + dl]);   // uniform -> SGPR
      float4 wsq = ld4(&ws[dh + dl]);   // uniform -> SGPR
      float4 xn0 = ld4(&tn[tx * 132 + dl]);
      float4 xn1 = ld4(&tn[(tx + 16) * 132 + dl]);
      float4 xe0 = ld4(&te[ty * 132 + dl]);
      float4 xe1 = ld4(&te[(ty + 16) * 132 + dl]);
#pragma unroll
      for (int j = 0; j < 2; ++j) {
        float4 xe = j ? xe1 : xe0;
#pragma unroll
        for (int i = 0; i < 2; ++i) {
          float4 xn = i ? xn1 : xn0;
          float u;
          u = fmaf(incv[j][i], wiq.x, xn.x + xe.x); u = fmaxf(u, 0.f); acc[j][i] = fmaf(u, wsq.x, acc[j][i]);
          u = fmaf(incv[j][i], wiq.y, xn.y + xe.y); u = fmaxf(u, 0.f); acc[j][i] = fmaf(u, wsq.y, acc[j][i]);
          u = fmaf(incv[j][i], wiq.z, xn.z + xe.z); u = fmaxf(u, 0.f); acc[j][i] = fmaf(u, wsq.z, acc[j][i]);
          u = fmaf(incv[j][i], wiq.w, xn.w + xe.w); u = fmaxf(u, 0.f); acc[j][i] = fmaf(u, wsq.w, acc[j][i]);
        }
      }
    }
  }
  const float b0 = bs[0];
#pragma unroll
  for (int j = 0; j < 2; ++j)
#pragma unroll
    for (int i = 0; i < 2; ++i) {
      float s = acc[j][i] + b0;
      pred[((rb + e0 + ty + 16 * j) << 8) + n0 + tx + 16 * i] = 1.f / (1.f + __expf(-s));
    }
}

// ---------------- transposed-A batched GEMM partials (upd). grid (16, 4, 4), block 256. scalar-A.
__global__ __launch_bounds__(256) void gemmt_part(const float* __restrict__ pred,
                                                  const float* __restrict__ nt,
                                                  float* __restrict__ part) {
  const int n0 = blockIdx.x * 16, b = blockIdx.y, e0 = blockIdx.z * 64;
  const int c = threadIdx.x;
  const float* Ab = pred + ((size_t)b << 16);
  const float* Bb = nt + ((size_t)b << 16);
  float acc[16];
#pragma unroll
  for (int r = 0; r < 16; ++r) acc[r] = 0.f;
#pragma unroll 2
  for (int e = e0; e < e0 + 64; ++e) {
    float w = Bb[((size_t)e << 8) + c];
    const float* ar = &Ab[((size_t)e << 8) + n0];
    float4 a0 = ld4(ar);        // uniform -> s_load_dwordx4
    float4 a1 = ld4(ar + 4);
    float4 a2 = ld4(ar + 8);
    float4 a3 = ld4(ar + 12);
    acc[0]  = fmaf(a0.x, w, acc[0]);   acc[1]  = fmaf(a0.y, w, acc[1]);
    acc[2]  = fmaf(a0.z, w, acc[2]);   acc[3]  = fmaf(a0.w, w, acc[3]);
    acc[4]  = fmaf(a1.x, w, acc[4]);   acc[5]  = fmaf(a1.y, w, acc[5]);
    acc[6]  = fmaf(a1.z, w, acc[6]);   acc[7]  = fmaf(a1.w, w, acc[7]);
    acc[8]  = fmaf(a2.x, w, acc[8]);   acc[9]  = fmaf(a2.y, w, acc[9]);
    acc[10] = fmaf(a2.z, w, acc[10]);  acc[11] = fmaf(a2.w, w, acc[11]);
    acc[12] = fmaf(a3.x, w, acc[12]);  acc[13] = fmaf(a3.y, w, acc[13]);
    acc[14] = fmaf(a3.z, w, acc[14]);  acc[15] = fmaf(a3.w, w, acc[15]);
  }
  float* pp = part + (((size_t)blockIdx.z * 1024 + b * 256 + n0) << 8) + c;
#pragma unroll
  for (int r = 0; r < 16; ++r) pp[(size_t)r * 256] = acc[r];
}

// ---------------- partial reduce + bias/rowterm/relu epilogue. grid 1024, block 256.
__global__ __launch_bounds__(256) void gred(const float* __restrict__ part,
                                            const float* __restrict__ bias,
                                            const float* __restrict__ rowterm,
                                            float* __restrict__ out, int relu) {
  const int idx = blockIdx.x * 256 + threadIdx.x;
  const int c = idx & 255;
  const int brow = idx >> 16;
  float s = part[idx] + part[idx + 262144] + part[idx + 524288] + part[idx + 786432];
  if (bias) s += bias[c];
  if (rowterm) s += rowterm[(brow << 8) + c];
  if (relu) s = fmaxf(s, 0.f);
  out[idx] = s;
}

__device__ inline void wred2(float& s, float& q) {
#pragma unroll
  for (int off = 32; off; off >>= 1) {
    s += __shfl_xor(s, off);
    q += __shfl_xor(q, off);
  }
}

// ---------------- reduce upd partials + LayerNorm(concat(x_in, nt, upd)) -> h. grid 256, block 256.
__global__ __launch_bounds__(256) void gredln768(const float* __restrict__ part,
                                                 const float* __restrict__ x_in,
                                                 const float* __restrict__ nt,
                                                 const float* __restrict__ g,
                                                 const float* __restrict__ be,
                                                 float* __restrict__ h) {
  const int row = blockIdx.x * 4 + (threadIdx.x >> 6);
  const int lane = threadIdx.x & 63;
  const int c4 = lane * 4;
  const size_t ro = (size_t)row * 256 + c4;
  float4 u = ld4(&part[ro]);
  float4 u1 = ld4(&part[ro + 262144]);
  float4 u2 = ld4(&part[ro + 524288]);
  float4 u3 = ld4(&part[ro + 786432]);
  u.x += u1.x + u2.x + u3.x;
  u.y += u1.y + u2.y + u3.y;
  u.z += u1.z + u2.z + u3.z;
  u.w += u1.w + u2.w + u3.w;
  float4 xi = ld4(&x_in[ro]);
  float4 nv = ld4(&nt[ro]);
  float s = xi.x + xi.y + xi.z + xi.w + nv.x + nv.y + nv.z + nv.w + u.x + u.y + u.z + u.w;
  float sq = xi.x * xi.x + xi.y * xi.y + xi.z * xi.z + xi.w * xi.w
           + nv.x * nv.x + nv.y * nv.y + nv.z * nv.z + nv.w * nv.w
           + u.x * u.x + u.y * u.y + u.z * u.z + u.w * u.w;
  wred2(s, sq);
  float mu = s * (1.f / 768.f);
  float rs = rsqrtf(sq * (1.f / 768.f) - mu * mu + LN_EPS);
  float* hr = h + (size_t)row * 768;
  {
    float4 g4 = ld4(&g[c4]), b4 = ld4(&be[c4]), o;
    o.x = (xi.x - mu) * rs * g4.x + b4.x;
    o.y = (xi.y - mu) * rs * g4.y + b4.y;
    o.z = (xi.z - mu) * rs * g4.z + b4.z;
    o.w = (xi.w - mu) * rs * g4.w + b4.w;
    st4(&hr[c4], o);
  }
  {
    float4 g4 = ld4(&g[256 + c4]), b4 = ld4(&be[256 + c4]), o;
    o.x = (nv.x - mu) * rs * g4.x + b4.x;
    o.y = (nv.y - mu) * rs * g4.y + b4.y;
    o.z = (nv.z - mu) * rs * g4.z + b4.z;
    o.w = (nv.w - mu) * rs * g4.w + b4.w;
    st4(&hr[256 + c4], o);
  }
  {
    float4 g4 = ld4(&g[512 + c4]), b4 = ld4(&be[512 + c4]), o;
    o.x = (u.x - mu) * rs * g4.x + b4.x;
    o.y = (u.y - mu) * rs * g4.y + b4.y;
    o.z = (u.z - mu) * rs * g4.z + b4.z;
    o.w = (u.w - mu) * rs * g4.w + b4.w;
    st4(&hr[512 + c4], o);
  }
}

// ---------------- reduce z partials + mt2 + residual + LayerNorm -> dst. grid 256, block 256.
__global__ __launch_bounds__(256) void gredln256(const float* __restrict__ part,
                                                 const float* __restrict__ nt,
                                                 const float* __restrict__ mt2,
                                                 const float* __restrict__ g,
                                                 const float* __restrict__ be,
                                                 float* __restrict__ dst) {
  const int row = blockIdx.x * 4 + (threadIdx.x >> 6);
  const int lane = threadIdx.x & 63;
  const int c4 = lane * 4;
  const int b = row >> 8;
  const size_t ro = (size_t)row * 256 + c4;
  float4 p0 = ld4(&part[ro]);
  float4 p1 = ld4(&part[ro + 262144]);
  float4 p2 = ld4(&part[ro + 524288]);
  float4 p3 = ld4(&part[ro + 786432]);
  float4 m4 = ld4(&mt2[(b << 8) + c4]);
  float4 nv = ld4(&nt[ro]);
  float4 x;
  x.x = nv.x + p0.x + p1.x + p2.x + p3.x + m4.x;
  x.y = nv.y + p0.y + p1.y + p2.y + p3.y + m4.y;
  x.z = nv.z + p0.z + p1.z + p2.z + p3.z + m4.z;
  x.w = nv.w + p0.w + p1.w + p2.w + p3.w + m4.w;
  float s = x.x + x.y + x.z + x.w;
  float sq = x.x * x.x + x.y * x.y + x.z * x.z + x.w * x.w;
  wred2(s, sq);
  float mu = s * (1.f / 256.f);
  float rs = rsqrtf(sq * (1.f / 256.f) - mu * mu + LN_EPS);
  float4 g4 = ld4(&g[c4]), b4 = ld4(&be[c4]), o;
  o.x = (x.x - mu) * rs * g4.x + b4.x;
  o.y = (x.y - mu) * rs * g4.y + b4.y;
  o.z = (x.z - mu) * rs * g4.z + b4.z;
  o.w = (x.w - mu) * rs * g4.w + b4.w;
  st4(&dst[ro], o);
}

// ---------------- column mean over n: ms[b][col] = mean_n X[b][n][col]. grid (4, Kd/256), block 256.
__global__ __launch_bounds__(256) void colmean(const float* __restrict__ X,
                                               float* __restrict__ ms, int Kd) {
  __shared__ float4 red[256];
  const int b = blockIdx.x;
  const int tid = threadIdx.x;
  const int lane = tid & 63, rg = tid >> 6;
  const int col0 = blockIdx.y * 256 + lane * 4;
  const float* xb = X + (size_t)b * 256 * Kd + col0 + (size_t)rg * 64 * Kd;
  float4 s = {0.f, 0.f, 0.f, 0.f};
#pragma unroll 8
  for (int n = 0; n < 64; ++n) {
    float4 v = ld4(&xb[(size_t)n * Kd]);
    s.x += v.x; s.y += v.y; s.z += v.z; s.w += v.w;
  }
  red[tid] = s;
  __syncthreads();
  if (tid < 64) {
    float4 a = red[tid], c = red[tid + 64], d = red[tid + 128], e = red[tid + 192];
    float4 o;
    o.x = (a.x + c.x + d.x + e.x) * (1.f / 256.f);
    o.y = (a.y + c.y + d.y + e.y) * (1.f / 256.f);
    o.z = (a.z + c.z + d.z + e.z) * (1.f / 256.f);
    o.w = (a.w + c.w + d.w + e.w) * (1.f / 256.f);
    st4(&ms[(size_t)b * Kd + col0], o);
  }
}

// ---------------- mt[b][c] = bias[c] + sum_k ms[b][k] * Wl[k][c]. grid 4, block 256. scalar-ms.
__global__ __launch_bounds__(256) void mtk(const float* __restrict__ ms,
                                           const float* __restrict__ Wl,
                                           const float* __restrict__ bias,
                                           float* __restrict__ mt, int Kd) {
  const int b = blockIdx.x, c = threadIdx.x;
  float acc = bias[c];
  const float* m = ms + (size_t)b * Kd;
  const float* wp = Wl + c;
#pragma unroll 4
  for (int k = 0; k < Kd; k += 4) {
    float4 mv = ld4(&m[k]);   // uniform -> s_load_dwordx4
    acc = fmaf(mv.x, wp[(size_t)k * 256], acc);
    acc = fmaf(mv.y, wp[(size_t)(k + 1) * 256], acc);
    acc = fmaf(mv.z, wp[(size_t)(k + 2) * 256], acc);
    acc = fmaf(mv.w, wp[(size_t)(k + 3) * 256], acc);
  }
  mt[(b << 8) + c] = acc;
}

extern "C" void kernel_launch(void* const* d_in, const int* in_sizes, int n_in,
                              void* d_out, int out_size, void* d_ws, size_t ws_size,
                              hipStream_t stream) {
  (void)in_sizes; (void)n_in; (void)out_size; (void)ws_size;
  const float* inputs = (const float*)d_in[0];
  const float* v_t    = (const float*)d_in[1];
  const float* i_t    = (const float*)d_in[2];
  const float* Wp     = (const float*)d_in[3];
  const float* bp     = (const float*)d_in[4];
  const float* Wx     = (const float*)d_in[5];
  const float* bx     = (const float*)d_in[6];
  const float* wi     = (const float*)d_in[7];
  const float* bi     = (const float*)d_in[8];
  const float* ws     = (const float*)d_in[9];
  const float* bs     = (const float*)d_in[10];
  const float* g_pre  = (const float*)d_in[11];
  const float* be_pre = (const float*)d_in[12];
  const float* g_n    = (const float*)d_in[13];
  const float* be_n   = (const float*)d_in[14];
  const float* W1g    = (const float*)d_in[15];
  const float* W1l    = (const float*)d_in[16];
  const float* b1     = (const float*)d_in[17];
  const float* W2g    = (const float*)d_in[18];
  const float* W2l    = (const float*)d_in[19];
  const float* b2     = (const float*)d_in[20];
  float* out = (float*)d_out;
  float* wsf = (float*)d_ws;
  float* x_in = wsf;                  // 262144
  float* ntA  = wsf + 262144;         // 262144
  float* ntB  = wsf + 524288;         // 262144
  float* h    = wsf + 786432;         // 786432
  float* h1   = wsf + 1572864;        // 262144
  float* partA = wsf + 1835008;       // 1048576
  float* ms1  = wsf + 2883584;        // 3072
  float* mt1  = wsf + 2886656;        // 1024
  float* ms2  = wsf + 2887680;        // 1024
  float* mt2  = wsf + 2888704;        // 1024

  hipMemcpyAsync(ntA, v_t, 262144 * sizeof(float), hipMemcpyDeviceToDevice, stream);

  // x_in = inputs @ Wp + bp  (full-K, 64 blocks)
  gemm_bias<<<64, 256, 0, stream>>>(inputs, Wp, bp, x_in, 128);

  float* ntCur = ntA;
  float* ntNxt = ntB;
  for (int t = 0; t < 3; ++t) {
    const float* incold = (t == 0) ? i_t : (out + (size_t)(t - 1) * 262144);
    float* pred = out + (size_t)t * 262144;
    // xp partials = ntCur @ Wx  (bx folded into adjfull staging)
    gemm_part<<<dim3(64, 4), 256, 0, stream>>>(ntCur, Wx, partA, 256, 64);
    // inc = sigmoid(sum_d relu(xp[n]+xp[e]+bi + inc*wi) * ws + bs)  [fused]
    adjfull<<<dim3(8, 8, 4), 256, 0, stream>>>(partA, incold, wi, bi, bx, ws, bs, pred);
    // upd partials = inc^T @ nt (per batch)
    gemmt_part<<<dim3(16, 4, 4), 256, 0, stream>>>(pred, ntCur, partA);
    // h = LN(concat(x_in, nt, upd))
    gredln768<<<256, 256, 0, stream>>>(partA, x_in, ntCur, g_pre, be_pre, h);
    // mt1 = b1 + mean_n(h) @ W1l
    colmean<<<dim3(4, 3), 256, 0, stream>>>(h, ms1, 768);
    mtk<<<4, 256, 0, stream>>>(ms1, W1l, b1, mt1, 768);
    // h1 = relu(h @ W1g + mt1)
    gemm_part<<<dim3(64, 4), 256, 0, stream>>>(h, W1g, partA, 768, 192);
    gred<<<1024, 256, 0, stream>>>(partA, nullptr, mt1, h1, 1);
    // mt2 = b2 + mean_n(h1) @ W2l
    colmean<<<dim3(4, 1), 256, 0, stream>>>(h1, ms2, 256);
    mtk<<<4, 256, 0, stream>>>(ms2, W2l, b2, mt2, 256);
    // nt = LN(nt + h1 @ W2g + mt2)
    gemm_part<<<dim3(64, 4), 256, 0, stream>>>(h1, W2g, partA, 256, 64);
    float* dst = (t == 2) ? (out + 786432) : ntNxt;
    gredln256<<<256, 256, 0, stream>>>(partA, ntCur, mt2, g_n, be_n, dst);
    float* tmp = ntCur; ntCur = ntNxt; ntNxt = tmp;
  }
  // final inc output = preds[2]
  hipMemcpyAsync(out + 1048576, out + 524288, 262144 * sizeof(float),
                 hipMemcpyDeviceToDevice, stream);
}

// Round 3
// 269.376 us; speedup vs baseline: 2.0260x; 2.0260x over previous
//
#include <hip/hip_runtime.h>
#include <cstddef>

#define LN_EPS 1e-5f

__device__ inline float4 ld4(const float* p) { return *reinterpret_cast<const float4*>(p); }
__device__ inline void st4(float* p, float4 v) { *reinterpret_cast<float4*>(p) = v; }

// ---------------- tiled GEMM: 64x64 tile, 4x4 micro, KSTEP 16.
// grid (16 Mtiles, 4 Ntiles, KS), block 256.
// bias==nullptr: writes partials part[kz][row][c] (kz=blockIdx.z, stride 262144).
// bias!=nullptr: (grid.z==1) writes out[row][c] = acc + bias[c].
__global__ __launch_bounds__(256) void gemm64(const float* __restrict__ A,
                                              const float* __restrict__ W,
                                              const float* __restrict__ bias,
                                              float* __restrict__ dst,
                                              int K, int chunk) {
  const int row0 = blockIdx.x * 64, col0 = blockIdx.y * 64;
  const int k0 = blockIdx.z * chunk;
  __shared__ float At[16][68];  // [kk][row]  (transposed A tile)
  __shared__ float Ws[16][68];  // [kk][col]
  const int tid = threadIdx.x;
  const int tx = tid & 15, ty = tid >> 4;
  float acc[4][4] = {{0.f}};
  const int arow = tid >> 2;          // 0..63
  const int ak4 = (tid & 3) * 4;      // 0,4,8,12
  const int wk = tid >> 4;            // 0..15
  const int wc4 = (tid & 15) * 4;     // 0..60
  for (int ks = 0; ks < chunk; ks += 16) {
    float4 av = ld4(&A[(size_t)(row0 + arow) * K + k0 + ks + ak4]);
    float4 wv = ld4(&W[(size_t)(k0 + ks + wk) * 256 + col0 + wc4]);
    __syncthreads();   // previous iteration's reads complete
    At[ak4 + 0][arow] = av.x;
    At[ak4 + 1][arow] = av.y;
    At[ak4 + 2][arow] = av.z;
    At[ak4 + 3][arow] = av.w;
    st4(&Ws[wk][wc4], wv);
    __syncthreads();   // writes visible
#pragma unroll
    for (int kk = 0; kk < 16; ++kk) {
      float4 a = ld4(&At[kk][ty * 4]);
      float4 w = ld4(&Ws[kk][tx * 4]);
      acc[0][0] = fmaf(a.x, w.x, acc[0][0]); acc[0][1] = fmaf(a.x, w.y, acc[0][1]);
      acc[0][2] = fmaf(a.x, w.z, acc[0][2]); acc[0][3] = fmaf(a.x, w.w, acc[0][3]);
      acc[1][0] = fmaf(a.y, w.x, acc[1][0]); acc[1][1] = fmaf(a.y, w.y, acc[1][1]);
      acc[1][2] = fmaf(a.y, w.z, acc[1][2]); acc[1][3] = fmaf(a.y, w.w, acc[1][3]);
      acc[2][0] = fmaf(a.z, w.x, acc[2][0]); acc[2][1] = fmaf(a.z, w.y, acc[2][1]);
      acc[2][2] = fmaf(a.z, w.z, acc[2][2]); acc[2][3] = fmaf(a.z, w.w, acc[2][3]);
      acc[3][0] = fmaf(a.w, w.x, acc[3][0]); acc[3][1] = fmaf(a.w, w.y, acc[3][1]);
      acc[3][2] = fmaf(a.w, w.z, acc[3][2]); acc[3][3] = fmaf(a.w, w.w, acc[3][3]);
    }
  }
  if (bias) {
    const float* bc = bias + col0 + tx * 4;
    float4 b4 = ld4(bc);
#pragma unroll
    for (int i = 0; i < 4; ++i) {
      float4 o;
      o.x = acc[i][0] + b4.x; o.y = acc[i][1] + b4.y;
      o.z = acc[i][2] + b4.z; o.w = acc[i][3] + b4.w;
      st4(&dst[(size_t)(row0 + ty * 4 + i) * 256 + col0 + tx * 4], o);
    }
  } else {
    float* pp = dst + (size_t)blockIdx.z * 262144;
#pragma unroll
    for (int i = 0; i < 4; ++i) {
      float4 o = {acc[i][0], acc[i][1], acc[i][2], acc[i][3]};
      st4(&pp[(size_t)(row0 + ty * 4 + i) * 256 + col0 + tx * 4], o);
    }
  }
}

// ---------------- transposed-A batched GEMM (upd): part[kc][b*256+n][c] = sum_e pred[b][e][n]*nt[b][e][c]
// grid (4 ntiles, 4 ctiles, 16 = b*4+kc), block 256. KSTEP 16, e-chunk 64.
__global__ __launch_bounds__(256) void gemmt64(const float* __restrict__ pred,
                                               const float* __restrict__ nt,
                                               float* __restrict__ part) {
  const int n0 = blockIdx.x * 64, col0 = blockIdx.y * 64;
  const int b = blockIdx.z >> 2, kc = blockIdx.z & 3;
  const int k0 = kc * 64;
  __shared__ float At[16][68];  // [ee][n]
  __shared__ float Ws[16][68];  // [ee][c]
  const int tid = threadIdx.x;
  const int tx = tid & 15, ty = tid >> 4;
  const float* Ab = pred + ((size_t)b << 16);
  const float* Bb = nt + ((size_t)b << 16);
  float acc[4][4] = {{0.f}};
  const int ee = tid >> 4;            // 0..15
  const int q4 = (tid & 15) * 4;      // 0..60
  for (int ks = 0; ks < 64; ks += 16) {
    float4 av = ld4(&Ab[((size_t)(k0 + ks + ee) << 8) + n0 + q4]);
    float4 wv = ld4(&Bb[((size_t)(k0 + ks + ee) << 8) + col0 + q4]);
    __syncthreads();
    st4(&At[ee][q4], av);
    st4(&Ws[ee][q4], wv);
    __syncthreads();
#pragma unroll
    for (int kk = 0; kk < 16; ++kk) {
      float4 a = ld4(&At[kk][ty * 4]);
      float4 w = ld4(&Ws[kk][tx * 4]);
      acc[0][0] = fmaf(a.x, w.x, acc[0][0]); acc[0][1] = fmaf(a.x, w.y, acc[0][1]);
      acc[0][2] = fmaf(a.x, w.z, acc[0][2]); acc[0][3] = fmaf(a.x, w.w, acc[0][3]);
      acc[1][0] = fmaf(a.y, w.x, acc[1][0]); acc[1][1] = fmaf(a.y, w.y, acc[1][1]);
      acc[1][2] = fmaf(a.y, w.z, acc[1][2]); acc[1][3] = fmaf(a.y, w.w, acc[1][3]);
      acc[2][0] = fmaf(a.z, w.x, acc[2][0]); acc[2][1] = fmaf(a.z, w.y, acc[2][1]);
      acc[2][2] = fmaf(a.z, w.z, acc[2][2]); acc[2][3] = fmaf(a.z, w.w, acc[2][3]);
      acc[3][0] = fmaf(a.w, w.x, acc[3][0]); acc[3][1] = fmaf(a.w, w.y, acc[3][1]);
      acc[3][2] = fmaf(a.w, w.z, acc[3][2]); acc[3][3] = fmaf(a.w, w.w, acc[3][3]);
    }
  }
  float* pp = part + (size_t)kc * 262144;
#pragma unroll
  for (int i = 0; i < 4; ++i) {
    float4 o = {acc[i][0], acc[i][1], acc[i][2], acc[i][3]};
    st4(&pp[(((size_t)b << 8) + n0 + ty * 4 + i) * 256 + col0 + tx * 4], o);
  }
}

// ---------------- fused adjacency (round-1, verified): xp partial-sum staging + relu-d-reduce + sigmoid
// grid (8, 8, 4), block 256.
__global__ __launch_bounds__(256) void adjfull(const float* __restrict__ part,
                                               const float* __restrict__ incold,
                                               const float* __restrict__ wi,
                                               const float* __restrict__ bi,
                                               const float* __restrict__ bx,
                                               const float* __restrict__ ws,
                                               const float* __restrict__ bs,
                                               float* __restrict__ pred,
                                               float* __restrict__ pred2) {
  __shared__ float lds[2 * 32 * 132];
  float* tn = lds;
  float* te = lds + 32 * 132;
  const int n0 = blockIdx.x * 32, e0 = blockIdx.y * 32, b = blockIdx.z;
  const int tid = threadIdx.x;
  const size_t rb = (size_t)b * 256;
  const int tx = tid & 15, ty = tid >> 4;
  float incv[2][2], acc[2][2];
#pragma unroll
  for (int j = 0; j < 2; ++j)
#pragma unroll
    for (int i = 0; i < 2; ++i) {
      incv[j][i] = incold[((rb + e0 + ty + 16 * j) << 8) + n0 + tx + 16 * i];
      acc[j][i] = 0.f;
    }
  for (int dh = 0; dh < 256; dh += 128) {
    if (dh) __syncthreads();
#pragma unroll
    for (int s = 0; s < 4; ++s) {
      int idx = tid + s * 256;
      int row = idx >> 5;
      int d = dh + (idx & 31) * 4;
      float4 bxv = ld4(&bx[d]);
      {
        size_t o = ((rb + n0 + row) << 8) + d;
        float4 p0 = ld4(&part[o]);
        float4 p1 = ld4(&part[o + 262144]);
        float4 p2 = ld4(&part[o + 524288]);
        float4 p3 = ld4(&part[o + 786432]);
        float4 v;
        v.x = p0.x + p1.x + p2.x + p3.x + bxv.x;
        v.y = p0.y + p1.y + p2.y + p3.y + bxv.y;
        v.z = p0.z + p1.z + p2.z + p3.z + bxv.z;
        v.w = p0.w + p1.w + p2.w + p3.w + bxv.w;
        st4(&tn[row * 132 + (d - dh)], v);
      }
      {
        size_t o = ((rb + e0 + row) << 8) + d;
        float4 p0 = ld4(&part[o]);
        float4 p1 = ld4(&part[o + 262144]);
        float4 p2 = ld4(&part[o + 524288]);
        float4 p3 = ld4(&part[o + 786432]);
        float4 bv = ld4(&bi[d]);
        float4 v;
        v.x = p0.x + p1.x + p2.x + p3.x + bxv.x + bv.x;
        v.y = p0.y + p1.y + p2.y + p3.y + bxv.y + bv.y;
        v.z = p0.z + p1.z + p2.z + p3.z + bxv.z + bv.z;
        v.w = p0.w + p1.w + p2.w + p3.w + bxv.w + bv.w;
        st4(&te[row * 132 + (d - dh)], v);
      }
    }
    __syncthreads();
#pragma unroll 4
    for (int dl = 0; dl < 128; dl += 4) {
      float4 wiq = ld4(&wi[dh + dl]);
      float4 wsq = ld4(&ws[dh + dl]);
      float4 xn0 = ld4(&tn[tx * 132 + dl]);
      float4 xn1 = ld4(&tn[(tx + 16) * 132 + dl]);
      float4 xe0 = ld4(&te[ty * 132 + dl]);
      float4 xe1 = ld4(&te[(ty + 16) * 132 + dl]);
#pragma unroll
      for (int j = 0; j < 2; ++j) {
        float4 xe = j ? xe1 : xe0;
#pragma unroll
        for (int i = 0; i < 2; ++i) {
          float4 xn = i ? xn1 : xn0;
          float u;
          u = fmaf(incv[j][i], wiq.x, xn.x + xe.x); u = fmaxf(u, 0.f); acc[j][i] = fmaf(u, wsq.x, acc[j][i]);
          u = fmaf(incv[j][i], wiq.y, xn.y + xe.y); u = fmaxf(u, 0.f); acc[j][i] = fmaf(u, wsq.y, acc[j][i]);
          u = fmaf(incv[j][i], wiq.z, xn.z + xe.z); u = fmaxf(u, 0.f); acc[j][i] = fmaf(u, wsq.z, acc[j][i]);
          u = fmaf(incv[j][i], wiq.w, xn.w + xe.w); u = fmaxf(u, 0.f); acc[j][i] = fmaf(u, wsq.w, acc[j][i]);
        }
      }
    }
  }
  const float b0 = bs[0];
#pragma unroll
  for (int j = 0; j < 2; ++j)
#pragma unroll
    for (int i = 0; i < 2; ++i) {
      float s = acc[j][i] + b0;
      float v = 1.f / (1.f + __expf(-s));
      size_t o = ((rb + e0 + ty + 16 * j) << 8) + n0 + tx + 16 * i;
      pred[o] = v;
      if (pred2) pred2[o] = v;
    }
}

// ---------------- partial reduce + mt-partials + relu epilogue (h1). grid 1024, block 256.
__global__ __launch_bounds__(256) void gred(const float* __restrict__ part,
                                            const float* __restrict__ mtp,
                                            int nks,
                                            float* __restrict__ out, int relu) {
  const int idx = blockIdx.x * 256 + threadIdx.x;
  const int c = idx & 255;
  const int b = idx >> 16;
  float s = part[idx] + part[idx + 262144] + part[idx + 524288] + part[idx + 786432];
  for (int k2 = 0; k2 < nks; ++k2) s += mtp[((size_t)(k2 * 4 + b) << 8) + c];
  if (relu) s = fmaxf(s, 0.f);
  out[idx] = s;
}

__device__ inline void wred2(float& s, float& q) {
#pragma unroll
  for (int off = 32; off; off >>= 1) {
    s += __shfl_xor(s, off);
    q += __shfl_xor(q, off);
  }
}

// ---------------- reduce upd partials + LayerNorm(concat(x_in, nt, upd)) -> h. grid 256, block 256.
__global__ __launch_bounds__(256) void gredln768(const float* __restrict__ part,
                                                 const float* __restrict__ x_in,
                                                 const float* __restrict__ nt,
                                                 const float* __restrict__ g,
                                                 const float* __restrict__ be,
                                                 float* __restrict__ h) {
  const int row = blockIdx.x * 4 + (threadIdx.x >> 6);
  const int lane = threadIdx.x & 63;
  const int c4 = lane * 4;
  const size_t ro = (size_t)row * 256 + c4;
  float4 u = ld4(&part[ro]);
  float4 u1 = ld4(&part[ro + 262144]);
  float4 u2 = ld4(&part[ro + 524288]);
  float4 u3 = ld4(&part[ro + 786432]);
  u.x += u1.x + u2.x + u3.x;
  u.y += u1.y + u2.y + u3.y;
  u.z += u1.z + u2.z + u3.z;
  u.w += u1.w + u2.w + u3.w;
  float4 xi = ld4(&x_in[ro]);
  float4 nv = ld4(&nt[ro]);
  float s = xi.x + xi.y + xi.z + xi.w + nv.x + nv.y + nv.z + nv.w + u.x + u.y + u.z + u.w;
  float sq = xi.x * xi.x + xi.y * xi.y + xi.z * xi.z + xi.w * xi.w
           + nv.x * nv.x + nv.y * nv.y + nv.z * nv.z + nv.w * nv.w
           + u.x * u.x + u.y * u.y + u.z * u.z + u.w * u.w;
  wred2(s, sq);
  float mu = s * (1.f / 768.f);
  float rs = rsqrtf(sq * (1.f / 768.f) - mu * mu + LN_EPS);
  float* hr = h + (size_t)row * 768;
  {
    float4 g4 = ld4(&g[c4]), b4 = ld4(&be[c4]), o;
    o.x = (xi.x - mu) * rs * g4.x + b4.x;
    o.y = (xi.y - mu) * rs * g4.y + b4.y;
    o.z = (xi.z - mu) * rs * g4.z + b4.z;
    o.w = (xi.w - mu) * rs * g4.w + b4.w;
    st4(&hr[c4], o);
  }
  {
    float4 g4 = ld4(&g[256 + c4]), b4 = ld4(&be[256 + c4]), o;
    o.x = (nv.x - mu) * rs * g4.x + b4.x;
    o.y = (nv.y - mu) * rs * g4.y + b4.y;
    o.z = (nv.z - mu) * rs * g4.z + b4.z;
    o.w = (nv.w - mu) * rs * g4.w + b4.w;
    st4(&hr[256 + c4], o);
  }
  {
    float4 g4 = ld4(&g[512 + c4]), b4 = ld4(&be[512 + c4]), o;
    o.x = (u.x - mu) * rs * g4.x + b4.x;
    o.y = (u.y - mu) * rs * g4.y + b4.y;
    o.z = (u.z - mu) * rs * g4.z + b4.z;
    o.w = (u.w - mu) * rs * g4.w + b4.w;
    st4(&hr[512 + c4], o);
  }
}

// ---------------- reduce z partials + mt2-partials + residual + LayerNorm -> dst. grid 256, block 256.
__global__ __launch_bounds__(256) void gredln256(const float* __restrict__ part,
                                                 const float* __restrict__ nt,
                                                 const float* __restrict__ mt2p,
                                                 const float* __restrict__ g,
                                                 const float* __restrict__ be,
                                                 float* __restrict__ dst) {
  const int row = blockIdx.x * 4 + (threadIdx.x >> 6);
  const int lane = threadIdx.x & 63;
  const int c4 = lane * 4;
  const int b = row >> 8;
  const size_t ro = (size_t)row * 256 + c4;
  float4 p0 = ld4(&part[ro]);
  float4 p1 = ld4(&part[ro + 262144]);
  float4 p2 = ld4(&part[ro + 524288]);
  float4 p3 = ld4(&part[ro + 786432]);
  float4 m4 = {0.f, 0.f, 0.f, 0.f};
#pragma unroll
  for (int k2 = 0; k2 < 4; ++k2) {
    float4 mv = ld4(&mt2p[((size_t)(k2 * 4 + b) << 8) + c4]);
    m4.x += mv.x; m4.y += mv.y; m4.z += mv.z; m4.w += mv.w;
  }
  float4 nv = ld4(&nt[ro]);
  float4 x;
  x.x = nv.x + p0.x + p1.x + p2.x + p3.x + m4.x;
  x.y = nv.y + p0.y + p1.y + p2.y + p3.y + m4.y;
  x.z = nv.z + p0.z + p1.z + p2.z + p3.z + m4.z;
  x.w = nv.w + p0.w + p1.w + p2.w + p3.w + m4.w;
  float s = x.x + x.y + x.z + x.w;
  float sq = x.x * x.x + x.y * x.y + x.z * x.z + x.w * x.w;
  wred2(s, sq);
  float mu = s * (1.f / 256.f);
  float rs = rsqrtf(sq * (1.f / 256.f) - mu * mu + LN_EPS);
  float4 g4 = ld4(&g[c4]), b4 = ld4(&be[c4]), o;
  o.x = (x.x - mu) * rs * g4.x + b4.x;
  o.y = (x.y - mu) * rs * g4.y + b4.y;
  o.z = (x.z - mu) * rs * g4.z + b4.z;
  o.w = (x.w - mu) * rs * g4.w + b4.w;
  st4(&dst[ro], o);
}

// ---------------- column mean over n: ms[b][col] = mean_n X[b][n][col]. grid (4, Kd/256), block 256.
__global__ __launch_bounds__(256) void colmean(const float* __restrict__ X,
                                               float* __restrict__ ms, int Kd) {
  __shared__ float4 red[256];
  const int b = blockIdx.x;
  const int tid = threadIdx.x;
  const int lane = tid & 63, rg = tid >> 6;
  const int col0 = blockIdx.y * 256 + lane * 4;
  const float* xb = X + (size_t)b * 256 * Kd + col0 + (size_t)rg * 64 * Kd;
  float4 s = {0.f, 0.f, 0.f, 0.f};
#pragma unroll 8
  for (int n = 0; n < 64; ++n) {
    float4 v = ld4(&xb[(size_t)n * Kd]);
    s.x += v.x; s.y += v.y; s.z += v.z; s.w += v.w;
  }
  red[tid] = s;
  __syncthreads();
  if (tid < 64) {
    float4 a = red[tid], c = red[tid + 64], d = red[tid + 128], e = red[tid + 192];
    float4 o;
    o.x = (a.x + c.x + d.x + e.x) * (1.f / 256.f);
    o.y = (a.y + c.y + d.y + e.y) * (1.f / 256.f);
    o.z = (a.z + c.z + d.z + e.z) * (1.f / 256.f);
    o.w = (a.w + c.w + d.w + e.w) * (1.f / 256.f);
    st4(&ms[(size_t)b * Kd + col0], o);
  }
}

// ---------------- split-k mean-linear term: mtp[ks][b][c] = (ks==0? bias[c]:0) + sum_{k in chunk64} ms[b][k]*Wl[k][c]
// grid (4 b, Kd/64), block 256.
__global__ __launch_bounds__(256) void mtk_ks(const float* __restrict__ ms,
                                              const float* __restrict__ Wl,
                                              const float* __restrict__ bias,
                                              float* __restrict__ mtp, int Kd) {
  __shared__ float m64[64];
  const int b = blockIdx.x, ks = blockIdx.y, c = threadIdx.x;
  const int k0 = ks * 64;
  if (c < 16) st4(&m64[c * 4], ld4(&ms[(size_t)b * Kd + k0 + c * 4]));
  __syncthreads();
  float acc = (ks == 0) ? bias[c] : 0.f;
  const float* wp = Wl + (size_t)k0 * 256 + c;
#pragma unroll 8
  for (int k = 0; k < 64; ++k) acc = fmaf(m64[k], wp[(size_t)k * 256], acc);
  mtp[((size_t)(ks * 4 + b) << 8) + c] = acc;
}

extern "C" void kernel_launch(void* const* d_in, const int* in_sizes, int n_in,
                              void* d_out, int out_size, void* d_ws, size_t ws_size,
                              hipStream_t stream) {
  (void)in_sizes; (void)n_in; (void)out_size; (void)ws_size;
  const float* inputs = (const float*)d_in[0];
  const float* v_t    = (const float*)d_in[1];
  const float* i_t    = (const float*)d_in[2];
  const float* Wp     = (const float*)d_in[3];
  const float* bp     = (const float*)d_in[4];
  const float* Wx     = (const float*)d_in[5];
  const float* bx     = (const float*)d_in[6];
  const float* wi     = (const float*)d_in[7];
  const float* bi     = (const float*)d_in[8];
  const float* ws     = (const float*)d_in[9];
  const float* bs     = (const float*)d_in[10];
  const float* g_pre  = (const float*)d_in[11];
  const float* be_pre = (const float*)d_in[12];
  const float* g_n    = (const float*)d_in[13];
  const float* be_n   = (const float*)d_in[14];
  const float* W1g    = (const float*)d_in[15];
  const float* W1l    = (const float*)d_in[16];
  const float* b1     = (const float*)d_in[17];
  const float* W2g    = (const float*)d_in[18];
  const float* W2l    = (const float*)d_in[19];
  const float* b2     = (const float*)d_in[20];
  float* out = (float*)d_out;
  float* wsf = (float*)d_ws;
  float* x_in  = wsf;                  // 262144
  float* ntA   = wsf + 262144;         // 262144
  float* ntB   = wsf + 524288;         // 262144
  float* h     = wsf + 786432;         // 786432
  float* h1    = wsf + 1572864;        // 262144
  float* part  = wsf + 1835008;        // 1048576
  float* ms1   = wsf + 2883584;        // 3072
  float* mt1p  = wsf + 2886656;        // 12288 (12 ks x 4 b x 256)
  float* ms2   = wsf + 2898944;        // 1024
  float* mt2p  = wsf + 2899968;        // 4096  (4 ks x 4 b x 256)

  // x_in = inputs @ Wp + bp  (full-K, bias epilogue, 64 blocks)
  gemm64<<<dim3(16, 4, 1), 256, 0, stream>>>(inputs, Wp, bp, x_in, 128, 128);

  for (int t = 0; t < 3; ++t) {
    const float* ntCur = (t == 0) ? v_t : ((t == 1) ? ntA : ntB);
    float* dst = (t == 2) ? (out + 786432) : ((t == 0) ? ntA : ntB);
    const float* incold = (t == 0) ? i_t : (out + (size_t)(t - 1) * 262144);
    float* pred = out + (size_t)t * 262144;
    float* pred2 = (t == 2) ? (out + 1048576) : nullptr;
    // xp partials = ntCur @ Wx
    gemm64<<<dim3(16, 4, 4), 256, 0, stream>>>(ntCur, Wx, nullptr, part, 256, 64);
    // inc = sigmoid(sum_d relu(xp[n]+xp[e]+bi + inc*wi) * ws + bs)
    adjfull<<<dim3(8, 8, 4), 256, 0, stream>>>(part, incold, wi, bi, bx, ws, bs, pred, pred2);
    // upd partials = inc^T @ nt (per batch)
    gemmt64<<<dim3(4, 4, 16), 256, 0, stream>>>(pred, ntCur, part);
    // h = LN(concat(x_in, nt, upd))
    gredln768<<<256, 256, 0, stream>>>(part, x_in, ntCur, g_pre, be_pre, h);
    // mt1 partials = b1 + mean_n(h) @ W1l
    colmean<<<dim3(4, 3), 256, 0, stream>>>(h, ms1, 768);
    mtk_ks<<<dim3(4, 12), 256, 0, stream>>>(ms1, W1l, b1, mt1p, 768);
    // h1 = relu(h @ W1g + mt1)
    gemm64<<<dim3(16, 4, 4), 256, 0, stream>>>(h, W1g, nullptr, part, 768, 192);
    gred<<<1024, 256, 0, stream>>>(part, mt1p, 12, h1, 1);
    // mt2 partials = b2 + mean_n(h1) @ W2l
    colmean<<<dim3(4, 1), 256, 0, stream>>>(h1, ms2, 256);
    mtk_ks<<<dim3(4, 4), 256, 0, stream>>>(ms2, W2l, b2, mt2p, 256);
    // nt' = LN(nt + h1 @ W2g + mt2)
    gemm64<<<dim3(16, 4, 4), 256, 0, stream>>>(h1, W2g, nullptr, part, 256, 64);
    gredln256<<<256, 256, 0, stream>>>(part, ntCur, mt2p, g_n, be_n, dst);
  }
}